// Round 7
// baseline (76.612 us; speedup 1.0000x reference)
//
#include <hip/hip_runtime.h>

#define Bv 16
#define Cv 64
#define Sv 2048
#define NSEG 32           // pli sample-groups per batch (64 samples each)
#define SSEG 64           // samples per pli group
#define ROWS 68           // pli LDS row stride in words (64 ch + 4 pad)
#define NTILE 144         // triangle tiles: dq in 0..8 x qi in 0..15
#define MAGICF 0x4F1BBCDCu   // flag value; workspace poison-fill resets flags each iter

typedef unsigned long long u64t;

// Forward DIF butterfly: u' = u+v ; v' = (u-v)*w
__device__ __forceinline__ void bf_f(float2& u, float2& v, const float2 w) {
    const float dr = u.x - v.x, di = u.y - v.y;
    u.x += v.x; u.y += v.y;
    v.x = dr * w.x - di * w.y;
    v.y = dr * w.y + di * w.x;
}
// Inverse DIT butterfly: v' = v*conj(w) ; u' = u+v' ; l' = u-v'
__device__ __forceinline__ void bf_i(float2& u, float2& v, const float2 w) {
    const float vr = v.x * w.x + v.y * w.y;
    const float vi = v.y * w.x - v.x * w.y;
    v.x = u.x - vr; v.y = u.y - vi;
    u.x += vr; u.y += vi;
}
__device__ __forceinline__ float2 csq(const float2 a) {
    return make_float2(a.x * a.x - a.y * a.y, 2.0f * a.x * a.y);
}
__device__ __forceinline__ float2 cm1(const float2 a) {   // a * e^{-i pi/4}
    const float cq = 0.70710678118654752f;
    return make_float2(cq * (a.x + a.y), cq * (a.y - a.x));
}
__device__ __forceinline__ float2 cmi(const float2 a) {   // a * e^{-i pi/2}
    return make_float2(a.y, -a.x);
}
// Bank-conflict-breaking storage map for the FFT scratch: n -> n + n/8.
__device__ __forceinline__ int pad(int n) { return n + (n >> 3); }

// Exact-antipodal pseudoangle (R6): monotone circle map, u(th+pi)==u(th)+2^31.
__device__ __forceinline__ unsigned int pang(const float x, const float h) {
    const float p = h * __builtin_amdgcn_rcpf(fabsf(x) + fabsf(h));
    const int i = (int)(p * 1073741824.0f);   // p * 2^30
    return (x >= 0.0f) ? (unsigned int)i : 0x80000000u - (unsigned int)i;
}

// Agent-scope (LLC-direct, write-through) accessors. No fences anywhere (R4
// lesson). R7: all bulk paths are 64-bit to HALVE the uncached request count
// (the fabric serves sc0/sc1 accesses per-request, no L2 dedup).
__device__ __forceinline__ void st_agent(unsigned int* p, unsigned int v) {
    __hip_atomic_store(p, v, __ATOMIC_RELAXED, __HIP_MEMORY_SCOPE_AGENT);
}
__device__ __forceinline__ unsigned int ld_agent(const unsigned int* p) {
    return __hip_atomic_load((unsigned int*)p, __ATOMIC_RELAXED, __HIP_MEMORY_SCOPE_AGENT);
}
__device__ __forceinline__ void st_agent64(u64t* p, u64t v) {
    __hip_atomic_store(p, v, __ATOMIC_RELAXED, __HIP_MEMORY_SCOPE_AGENT);
}
__device__ __forceinline__ u64t ld_agent64(const u64t* p) {
    return __hip_atomic_load((u64t*)p, __ATOMIC_RELAXED, __HIP_MEMORY_SCOPE_AGENT);
}
// Rendezvous: wave-parallel relaxed poll of the 32 flags of batch b. No fence.
__device__ __forceinline__ void wait_batch(const unsigned int* f, int t) {
    if (t < 32) {
        int guard = 0;
        while (ld_agent(&f[t]) != MAGICF && guard < (1 << 20)) {
            ++guard;
            __builtin_amdgcn_s_sleep(2);
        }
    }
    __syncthreads();
}

// ---------------------------------------------------------------------------
// Single kernel, 512 blocks x 256 threads, all resident (2 blocks/CU):
//   phase 0: Hilbert for channels 2blk,2blk+1 -> pseudoangles (u64 stores via
//            LDS transpose: each lane stores 8 contiguous u64, coalesced)
//   rendezvous flags1
//   phase 1: PLI sign counts, u64 staging loads, 2-sample add3 inner loop
//   rendezvous flags2
//   phase 2: tile-owned finalize: block (b,g) gathers its 4-5 tiles' packed
//            counts (no redundant reads), LDS byte-sum, direct+mirror writes
// ---------------------------------------------------------------------------
__global__ __launch_bounds__(256, 2) void pli_one(const float* __restrict__ x,
                                                  unsigned int* __restrict__ u,
                                                  unsigned int* __restrict__ part,
                                                  unsigned int* __restrict__ flags1,
                                                  unsigned int* __restrict__ flags2,
                                                  float* __restrict__ out) {
    // Time-shared LDS: FFT scratch / u32 staging / count tile / finalize tile
    __shared__ __align__(16) unsigned char shraw[(Sv + Sv / 8) * sizeof(float2)];
    float2* const zz = (float2*)shraw;
    unsigned int* const uL = (unsigned int*)shraw;
    const int t = threadIdx.x;
    const int blk = blockIdx.x;
    const int b = blk >> 5;          // batch
    const int g = blk & (NSEG - 1);  // sample group / finalize tile-slice

    // ===================== phase 0: Hilbert + pseudoangle quantize =====================
    {
        const int c0 = blk * 2;
        const float* x0 = x + (size_t)c0 * Sv;
        const float* x1 = x0 + Sv;

        const float PI = 3.14159265358979323846f;
        float2 bA4, bB4, bC2;
        sincosf(-PI * (float)t * (1.0f / 1024.0f), &bA4.y, &bA4.x);
        sincosf(-PI * (float)(t & 31) * (1.0f / 128.0f), &bB4.y, &bB4.x);
        sincosf(-PI * (float)(t & 7) * (1.0f / 16.0f), &bC2.y, &bC2.x);
        const float2 bA2 = csq(bA4), bA1 = csq(bA2);
        const float2 bB2 = csq(bB4), bB1 = csq(bB2);
        const float2 bC1 = csq(bC2);

        float xa[8], xb[8];
        float2 z[8];
        #pragma unroll
        for (int k = 0; k < 8; ++k) {
            xa[k] = x0[t + 256 * k];
            xb[k] = x1[t + 256 * k];
            z[k] = make_float2(xa[k], xb[k]);
        }

        // ---- fwd halves 1024,512,256 (stride 256) ----
        {
            const float2 w1 = cm1(bA4);
            bf_f(z[0], z[4], bA4);      bf_f(z[1], z[5], w1);
            bf_f(z[2], z[6], cmi(bA4)); bf_f(z[3], z[7], cmi(w1));
            const float2 wB = cmi(bA2);
            bf_f(z[0], z[2], bA2); bf_f(z[1], z[3], wB);
            bf_f(z[4], z[6], bA2); bf_f(z[5], z[7], wB);
            bf_f(z[0], z[1], bA1); bf_f(z[2], z[3], bA1);
            bf_f(z[4], z[5], bA1); bf_f(z[6], z[7], bA1);
        }
        #pragma unroll
        for (int k = 0; k < 8; ++k) zz[pad(t + 256 * k)] = z[k];
        __syncthreads();

        // ---- fwd halves 128,64,32 (stride 32) ----
        {
            const int r = t & 31, base = (t >> 5) * 256 + r;
            #pragma unroll
            for (int k = 0; k < 8; ++k) z[k] = zz[pad(base + 32 * k)];
            const float2 w1 = cm1(bB4);
            bf_f(z[0], z[4], bB4);      bf_f(z[1], z[5], w1);
            bf_f(z[2], z[6], cmi(bB4)); bf_f(z[3], z[7], cmi(w1));
            const float2 wB = cmi(bB2);
            bf_f(z[0], z[2], bB2); bf_f(z[1], z[3], wB);
            bf_f(z[4], z[6], bB2); bf_f(z[5], z[7], wB);
            bf_f(z[0], z[1], bB1); bf_f(z[2], z[3], bB1);
            bf_f(z[4], z[5], bB1); bf_f(z[6], z[7], bB1);
            #pragma unroll
            for (int k = 0; k < 8; ++k) zz[pad(base + 32 * k)] = z[k];
        }
        __syncthreads();

        // ---- fwd halves 16,8 (stride 8; two 4-sets) ----
        {
            const int r = t & 7, base0 = (t >> 3) * 32 + r, base1 = base0 + 1024;
            #pragma unroll
            for (int k = 0; k < 4; ++k) {
                z[k] = zz[pad(base0 + 8 * k)];
                z[4 + k] = zz[pad(base1 + 8 * k)];
            }
            const float2 wB = cmi(bC2);
            bf_f(z[0], z[2], bC2); bf_f(z[1], z[3], wB);
            bf_f(z[4], z[6], bC2); bf_f(z[5], z[7], wB);
            bf_f(z[0], z[1], bC1); bf_f(z[2], z[3], bC1);
            bf_f(z[4], z[5], bC1); bf_f(z[6], z[7], bC1);
            #pragma unroll
            for (int k = 0; k < 4; ++k) {
                zz[pad(base0 + 8 * k)] = z[k];
                zz[pad(base1 + 8 * k)] = z[4 + k];
            }
        }
        __syncthreads();

        // ---- fused: fwd 4,2,1 ; Hilbert filter * 1/N ; inv 1,2,4 ----
        {
            const int base = 8 * t;
            #pragma unroll
            for (int k = 0; k < 8; ++k) z[k] = zz[pad(base + k)];
            const float cq = 0.70710678118654752f;
            const float2 W1  = make_float2(1.0f, 0.0f);
            const float2 W41 = make_float2(cq, -cq);
            const float2 W42 = make_float2(0.0f, -1.0f);
            const float2 W43 = make_float2(-cq, -cq);
            bf_f(z[0], z[4], W1);  bf_f(z[1], z[5], W41);
            bf_f(z[2], z[6], W42); bf_f(z[3], z[7], W43);
            bf_f(z[0], z[2], W1); bf_f(z[1], z[3], W42);
            bf_f(z[4], z[6], W1); bf_f(z[5], z[7], W42);
            bf_f(z[0], z[1], W1); bf_f(z[2], z[3], W1);
            bf_f(z[4], z[5], W1); bf_f(z[6], z[7], W1);
            const float inv = 1.0f / (float)Sv;
            #pragma unroll
            for (int k = 0; k < 8; ++k) {
                const int kk = (int)(__brev((unsigned)(base + k)) >> 21);   // logical index!
                const float m = (kk == 0 || kk == Sv / 2) ? inv : (kk < Sv / 2 ? 2.0f * inv : 0.0f);
                z[k].x *= m; z[k].y *= m;
            }
            bf_i(z[0], z[1], W1); bf_i(z[2], z[3], W1);
            bf_i(z[4], z[5], W1); bf_i(z[6], z[7], W1);
            bf_i(z[0], z[2], W1); bf_i(z[1], z[3], W42);
            bf_i(z[4], z[6], W1); bf_i(z[5], z[7], W42);
            bf_i(z[0], z[4], W1);  bf_i(z[1], z[5], W41);
            bf_i(z[2], z[6], W42); bf_i(z[3], z[7], W43);
            #pragma unroll
            for (int k = 0; k < 8; ++k) zz[pad(base + k)] = z[k];
        }
        __syncthreads();

        // ---- inv halves 8,16 (stride 8; two 4-sets) ----
        {
            const int r = t & 7, base0 = (t >> 3) * 32 + r, base1 = base0 + 1024;
            #pragma unroll
            for (int k = 0; k < 4; ++k) {
                z[k] = zz[pad(base0 + 8 * k)];
                z[4 + k] = zz[pad(base1 + 8 * k)];
            }
            bf_i(z[0], z[1], bC1); bf_i(z[2], z[3], bC1);
            bf_i(z[4], z[5], bC1); bf_i(z[6], z[7], bC1);
            const float2 wB = cmi(bC2);
            bf_i(z[0], z[2], bC2); bf_i(z[1], z[3], wB);
            bf_i(z[4], z[6], bC2); bf_i(z[5], z[7], wB);
            #pragma unroll
            for (int k = 0; k < 4; ++k) {
                zz[pad(base0 + 8 * k)] = z[k];
                zz[pad(base1 + 8 * k)] = z[4 + k];
            }
        }
        __syncthreads();

        // ---- inv halves 32,64,128 (stride 32) ----
        {
            const int r = t & 31, base = (t >> 5) * 256 + r;
            #pragma unroll
            for (int k = 0; k < 8; ++k) z[k] = zz[pad(base + 32 * k)];
            bf_i(z[0], z[1], bB1); bf_i(z[2], z[3], bB1);
            bf_i(z[4], z[5], bB1); bf_i(z[6], z[7], bB1);
            const float2 wB = cmi(bB2);
            bf_i(z[0], z[2], bB2); bf_i(z[1], z[3], wB);
            bf_i(z[4], z[6], bB2); bf_i(z[5], z[7], wB);
            const float2 w1 = cm1(bB4);
            bf_i(z[0], z[4], bB4);      bf_i(z[1], z[5], w1);
            bf_i(z[2], z[6], cmi(bB4)); bf_i(z[3], z[7], cmi(w1));
            #pragma unroll
            for (int k = 0; k < 8; ++k) zz[pad(base + 32 * k)] = z[k];
        }
        __syncthreads();

        // ---- inv halves 256,512,1024 (stride 256) + LDS transpose + u64 stores ----
        {
            #pragma unroll
            for (int k = 0; k < 8; ++k) z[k] = zz[pad(t + 256 * k)];
            bf_i(z[0], z[1], bA1); bf_i(z[2], z[3], bA1);
            bf_i(z[4], z[5], bA1); bf_i(z[6], z[7], bA1);
            const float2 wB = cmi(bA2);
            bf_i(z[0], z[2], bA2); bf_i(z[1], z[3], wB);
            bf_i(z[4], z[6], bA2); bf_i(z[5], z[7], wB);
            const float2 w1 = cm1(bA4);
            bf_i(z[0], z[4], bA4);      bf_i(z[1], z[5], w1);
            bf_i(z[2], z[6], cmi(bA4)); bf_i(z[3], z[7], cmi(w1));

            // All zz reads of this section are done; barrier, then reuse LDS
            // as a u32 staging buffer uS[2][2048] so global stores can be u64.
            __syncthreads();
            unsigned int* const uS = (unsigned int*)shraw;
            #pragma unroll
            for (int k = 0; k < 8; ++k) {
                const int n = t + 256 * k;
                const float ha = z[k].y - xb[k];   // H(x_a) = Im(w) - x_b
                const float hb = xa[k] - z[k].x;   // H(x_b) = x_a - Re(w)
                uS[n]        = pang(xa[k], ha);
                uS[2048 + n] = pang(xb[k], hb);
            }
            __syncthreads();
            // channels c0,c0+1 are contiguous in u: 4096 u32 = 2048 u64.
            const u64t* uS64 = (const u64t*)shraw;
            u64t* ug = (u64t*)(u + (size_t)c0 * Sv);
            #pragma unroll
            for (int q = 0; q < 8; ++q) {
                const int m = q * 256 + t;         // consecutive lanes -> coalesced
                st_agent64(&ug[m], uS64[m]);
            }
        }
    }

    // Publish phase 0 (syncthreads drains vmcnt; agent stores are write-through).
    __syncthreads();
    if (t == 0) st_agent(&flags1[blk], MAGICF);

    wait_batch(flags1 + b * 32, t);

    // ===================== phase 1: PLI negative-sign counts =====================
    {
        const unsigned int* ub = u + (size_t)b * Cv * Sv + g * SSEG;

        // u64 staging: 8 loads/thread, issued back-to-back (one latency round).
        u64t r64[8];
        #pragma unroll
        for (int p = 0; p < 8; ++p) {
            const int idx = p * 256 + t;           // 0..2047 u64 units
            const int ch = idx >> 5;               // 64 channels
            const int s2 = idx & 31;               // u64 index within row (2 samples)
            r64[p] = ld_agent64((const u64t*)(ub + (size_t)ch * Sv) + s2);
        }
        #pragma unroll
        for (int p = 0; p < 8; ++p) {
            const int idx = p * 256 + t;
            const int ch = idx >> 5;
            const int s = (idx & 31) * 2;
            uL[s * ROWS + ch] = (unsigned int)r64[p];
            uL[(s + 1) * ROWS + ch] = (unsigned int)(r64[p] >> 32);
        }
        __syncthreads();

        if (t < NTILE) {
            const int qi = t & 15;
            const int dq = t >> 4;                  // 0..8
            const int i0 = qi * 4;
            const int j0 = ((qi + dq) & 15) * 4;
            int neg[4][4] = {};

            #pragma unroll 2
            for (int s = 0; s < SSEG; s += 2) {     // 2 samples/iter -> v_add3
                const uint4 ui0 = *(const uint4*)&uL[s * ROWS + i0];
                const uint4 uj0 = *(const uint4*)&uL[s * ROWS + j0];
                const uint4 ui1 = *(const uint4*)&uL[(s + 1) * ROWS + i0];
                const uint4 uj1 = *(const uint4*)&uL[(s + 1) * ROWS + j0];
                const unsigned int ia0[4] = {ui0.x, ui0.y, ui0.z, ui0.w};
                const unsigned int ja0[4] = {uj0.x, uj0.y, uj0.z, uj0.w};
                const unsigned int ia1[4] = {ui1.x, ui1.y, ui1.z, ui1.w};
                const unsigned int ja1[4] = {uj1.x, uj1.y, uj1.z, uj1.w};
                #pragma unroll
                for (int a = 0; a < 4; ++a) {
                    #pragma unroll
                    for (int c = 0; c < 4; ++c) {
                        neg[a][c] += (int)(((ia0[a] - ja0[c]) >> 31)
                                         + ((ia1[a] - ja1[c]) >> 31));
                    }
                }
            }

            u64t* Pb = (u64t*)(part + ((size_t)blk * NTILE + t) * 4);
            unsigned int pk[4];
            #pragma unroll
            for (int a = 0; a < 4; ++a)
                pk[a] = (unsigned)neg[a][0] | ((unsigned)neg[a][1] << 8)
                      | ((unsigned)neg[a][2] << 16) | ((unsigned)neg[a][3] << 24);
            st_agent64(&Pb[0], (u64t)pk[0] | ((u64t)pk[1] << 32));
            st_agent64(&Pb[1], (u64t)pk[2] | ((u64t)pk[3] << 32));
        }
    }

    __syncthreads();
    if (t == 0) st_agent(&flags2[blk], MAGICF);

    wait_batch(flags2 + b * 32, t);

    // ============ phase 2: tile-owned finalize (4-5 tiles per block) ============
    // Block (b,g) owns tiles {g+32l}. Gather each tile's packed counts for all
    // 32 groups exactly once (no redundant uncached reads), LDS byte-sum the 16
    // slots, write direct outputs + mirrors (dq 1..7; dq 0/8 self-covered).
    {
        const int nt = (g < 16) ? 5 : 4;
        u64t* const pT64 = (u64t*)shraw;
        unsigned int* const pTu = (unsigned int*)shraw;

        if (t < nt * 32) {
            const int l = t >> 5, s = t & 31;
            const int tau = g + 32 * l;
            const u64t* src = (const u64t*)(part + ((size_t)(b * 32 + s) * NTILE + tau) * 4);
            pT64[(l * 32 + s) * 2]     = ld_agent64(&src[0]);
            pT64[(l * 32 + s) * 2 + 1] = ld_agent64(&src[1]);
        }
        __syncthreads();

        if (t < nt * 16) {
            const int l = t >> 4, slot = t & 15;
            const int a = slot >> 2, c = slot & 3;
            const unsigned int* row = pTu + (l * 32) * 4 + a;
            const int sh = 8 * c;
            int negsum = 0;
            #pragma unroll 8
            for (int s = 0; s < 32; ++s)
                negsum += (int)((row[s * 4] >> sh) & 255u);

            const int tau = g + 32 * l;
            const int dq = tau >> 4, qi = tau & 15;
            const int qj = (qi + dq) & 15;
            const int i = qi * 4 + a, j = qj * 4 + c;
            const float pli = (i == j)
                ? 0.0f
                : fabsf((float)Sv - 2.0f * (float)negsum) * (1.0f / (float)Sv);
            float* ob = out + b * (Cv * Cv);
            ob[i * 64 + j] = pli;
            if (dq >= 1 && dq <= 7) ob[j * 64 + i] = pli;
        }
    }
}

extern "C" void kernel_launch(void* const* d_in, const int* in_sizes, int n_in,
                              void* d_out, int out_size, void* d_ws, size_t ws_size,
                              hipStream_t stream) {
    const float* x = (const float*)d_in[0];            // [B, C, S] fp32
    char* ws = (char*)d_ws;
    unsigned int* u      = (unsigned int*)ws;                       // 8 MB phases
    unsigned int* part   = (unsigned int*)(ws + (8u << 20));        // 1.13 MB partials
    unsigned int* flags1 = (unsigned int*)(ws + (16u << 20));       // 512 u32
    unsigned int* flags2 = (unsigned int*)(ws + (16u << 20) + 4096);
    float* out = (float*)d_out;                        // [B, C, C] fp32

    hipLaunchKernelGGL(pli_one, dim3(Bv * Cv / 2), dim3(256), 0, stream,
                       x, u, part, flags1, flags2, out);
}